// Round 1
// 626.890 us; speedup vs baseline: 1.1877x; 1.1877x over previous
//
#include <hip/hip_runtime.h>
#include <hip/hip_bf16.h>
#include <math.h>

#define DIM 256
#define NB 4
#define LQ 1000
#define MLPD 512
#define LIN 21824
#define ROWS_X 4000
#define ROWS_SRC 87296
#define ATT_SCALE 0.17677669529663687f  /* 32^-0.5 */
#define LDK 72   /* padded LDS row (bf16 elems): 144 B, 16B-aligned */

typedef __hip_bfloat16 bf16;
typedef __attribute__((ext_vector_type(8))) short short8;
typedef __attribute__((ext_vector_type(4))) float floatx4;

__device__ __forceinline__ float rdv(const void* p, int f, size_t i){
    if (f) return ((const float*)p)[i];
    unsigned u = ((unsigned)((const unsigned short*)p)[i]) << 16;
    union { unsigned u; float f; } c; c.u = u; return c.f;
}
__device__ __forceinline__ short f2bs(float v){
    bf16 h = __float2bfloat16(v);
    return *reinterpret_cast<short*>(&h);
}
__device__ __forceinline__ float bs2f(short s){
    union { unsigned u; float f; } c; c.u = ((unsigned)(unsigned short)s) << 16; return c.f;
}

// ---------- dtype detect ----------
__global__ void detect_kernel(const void* __restrict__ x, int* __restrict__ flag){
    const unsigned short* u = (const unsigned short*)x;
    int t = threadIdx.x;
    bool hit = false;
    #pragma unroll
    for (int k = 0; k < 4; ++k) {
        unsigned short b = u[(t*4 + k)*2];
        union { unsigned u; float f; } c; c.u = ((unsigned)b) << 16;
        if (!(fabsf(c.f) <= 1000.f)) hit = true;
    }
    unsigned long long m = __ballot(hit);
    __shared__ unsigned long long red[4];
    if ((t & 63) == 0) red[t >> 6] = m;
    __syncthreads();
    if (t == 0) flag[0] = ((red[0]|red[1]|red[2]|red[3]) != 0ULL) ? 1 : 0;
}

__global__ void conv_kernel(const void* __restrict__ in, float* __restrict__ out,
                            int n, const int* __restrict__ flag){
    int f = flag[0];
    int i = blockIdx.x*256 + threadIdx.x;
    if (i < n) out[i] = rdv(in, f, i);
}

// ---------- fused small-param conversions (incl. center_pos) ----------
struct PTab { const void* src[14]; float* dst[14]; int n[14]; };
__global__ void convs_kernel(PTab t, const int* __restrict__ flag){
    int f = flag[0];
    int j = blockIdx.y;
    int i = blockIdx.x*256 + threadIdx.x;
    if (i < t.n[j]) t.dst[j][i] = rdv(t.src[j], f, i);
}

// ---------- concat off_b|aw_b into oab[2][480] ----------
__global__ void catb_kernel(const void* __restrict__ offb, const void* __restrict__ awb,
                            const int* __restrict__ flag, float* __restrict__ oab){
    int f = flag[0];
    int layer = blockIdx.y;
    int idx = blockIdx.x*256 + threadIdx.x;
    if (idx >= 480) return;
    float v = (idx < 320) ? rdv(offb, f, (size_t)layer*320 + idx)
                          : rdv(awb,  f, (size_t)layer*160 + idx - 320);
    oab[layer*480 + idx] = v;
}

// ---------- all weight transposes in ONE launch: W[b][K][N] -> Wt[b][ldout][K] bf16 ----------
struct WT { const void* src[8]; short* dst[8]; int K[8]; int N[8]; int ld[8]; int ro[8]; };
__global__ void wtransall_kernel(WT t, const int* __restrict__ flag){
    int j = blockIdx.z >> 1, b = blockIdx.z & 1;
    int K = t.K[j], N = t.N[j];
    int k0 = blockIdx.x*32, n0 = blockIdx.y*32;
    if (k0 >= K || n0 >= N) return;   // uniform per block, before any sync
    int f = flag[0];
    __shared__ float tt[32][33];
    int tx = threadIdx.x & 31, ty = threadIdx.x >> 5;
    size_t base = (size_t)b * K * N;
    for (int i = ty; i < 32; i += 8) {
        int k = k0 + i, n = n0 + tx;
        tt[i][tx] = (k < K && n < N) ? rdv(t.src[j], f, base + (size_t)k*N + n) : 0.f;
    }
    __syncthreads();
    int ld = t.ld[j], ro = t.ro[j];
    for (int i = ty; i < 32; i += 8) {
        int n = n0 + i, k = k0 + tx;
        if (n < N && k < K)
            t.dst[j][(size_t)b*ld*K + (size_t)(ro+n)*K + k] = f2bs(tt[tx][i]);
    }
}

// ---------- pe directly from raw inputs (no dependency on conversions) ----------
__global__ void pe_kernel(const void* __restrict__ cp, const void* __restrict__ pw,
                          const void* __restrict__ pb, const int* __restrict__ flag,
                          float* __restrict__ pe){
    int f = flag[0];
    int row = blockIdx.x, t = threadIdx.x;
    float cx = rdv(cp, f, (size_t)row*2);
    float cy = rdv(cp, f, (size_t)row*2 + 1);
    pe[(size_t)row*DIM + t] = cx*rdv(pw, f, t) + cy*rdv(pw, f, DIM + t) + rdv(pb, f, t);
}

// ---------- per-row stats of src: one wave per row, shuffle-only ----------
__global__ __launch_bounds__(256) void stats2_kernel(const void* __restrict__ src,
                                                     const int* __restrict__ flag,
                                                     float2* __restrict__ stats){
    int f = flag[0];
    int wave = threadIdx.x >> 6, lane = threadIdx.x & 63;
    int row = blockIdx.x*4 + wave;
    float v0, v1, v2, v3;
    if (f) {
        float4 x = *(const float4*)((const float*)src + (size_t)row*DIM + lane*4);
        v0 = x.x; v1 = x.y; v2 = x.z; v3 = x.w;
    } else {
        ushort4 u = *(const ushort4*)((const unsigned short*)src + (size_t)row*DIM + lane*4);
        v0 = bs2f((short)u.x); v1 = bs2f((short)u.y);
        v2 = bs2f((short)u.z); v3 = bs2f((short)u.w);
    }
    float s  = v0 + v1 + v2 + v3;
    float s2 = v0*v0 + v1*v1 + v2*v2 + v3*v3;
    #pragma unroll
    for (int o = 32; o; o >>= 1) {
        s  += __shfl_xor(s,  o, 64);
        s2 += __shfl_xor(s2, o, 64);
    }
    if (lane == 0) {
        float mean = s * (1.f/DIM);
        float var  = s2 * (1.f/DIM) - mean*mean;
        stats[row] = make_float2(mean, rsqrtf(var + 1e-5f));
    }
}

// ---------- per-row stats of fp32 x [+pre]: one wave per row ----------
__global__ __launch_bounds__(256) void xstats_kernel(const float* __restrict__ a,
                                                     const float* __restrict__ pre,
                                                     float2* __restrict__ st){
    int wave = threadIdx.x >> 6, lane = threadIdx.x & 63;
    int row = blockIdx.x*4 + wave;
    float4 x = *(const float4*)(a + (size_t)row*DIM + lane*4);
    if (pre) {
        float4 p = *(const float4*)(pre + (size_t)row*DIM + lane*4);
        x.x += p.x; x.y += p.y; x.z += p.z; x.w += p.w;
    }
    float s  = x.x + x.y + x.z + x.w;
    float s2 = x.x*x.x + x.y*x.y + x.z*x.z + x.w*x.w;
    #pragma unroll
    for (int o = 32; o; o >>= 1) {
        s  += __shfl_xor(s,  o, 64);
        s2 += __shfl_xor(s2, o, 64);
    }
    if (lane == 0) {
        float mean = s * (1.f/DIM);
        float var  = s2 * (1.f/DIM) - mean*mean;
        st[row] = make_float2(mean, rsqrtf(var + 1e-5f));
    }
}

// ---------- MFMA GEMM 64x64: C = A' @ Wt^T (+bias)(gelu?)(+res) ----------
// AMODE: 0 = A fp32; 2 = A bf16; 3 = A fp32 with fused LN:
//   A' = (A [+Apre] - m)*rstd*ag + ab [+Apost]
template<int AMODE>
__global__ __launch_bounds__(256) void mgemm_kernel(
    const void* __restrict__ Asrc,
    const float2* __restrict__ ast, const float* __restrict__ ag, const float* __restrict__ ab,
    const float* __restrict__ Apre, const float* __restrict__ Apost,
    const short* __restrict__ Wt, const float* __restrict__ bias, const float* res,
    void* Cout, int M, int K, int N, int act, int cbf){
    __shared__ short As[64*LDK];
    __shared__ short Bs[64*LDK];
    int tid = threadIdx.x;
    int wave = tid >> 6, lane = tid & 63;
    int wm = wave >> 1, wn = wave & 1;
    int quad = lane >> 4, l16 = lane & 15;
    int row0 = blockIdx.x*64, col0 = blockIdx.y*64;
    floatx4 acc[2][2];
    #pragma unroll
    for (int i = 0; i < 2; ++i)
        #pragma unroll
        for (int j = 0; j < 2; ++j)
            acc[i][j] = (floatx4){0.f,0.f,0.f,0.f};

    int r  = tid >> 2;
    int kc = (tid & 3) * 16;
    int gr = row0 + r;
    int gc = col0 + r;
    const short8 z8 = {0,0,0,0,0,0,0,0};

    for (int k0 = 0; k0 < K; k0 += 64) {
        short8 a0 = z8, a1 = z8;
        if (gr < M) {
            if (AMODE == 2) {
                const short8* p = (const short8*)((const short*)Asrc + (size_t)gr*K + k0 + kc);
                a0 = p[0]; a1 = p[1];
            } else {
                const float4* p = (const float4*)((const float*)Asrc + (size_t)gr*K + k0 + kc);
                float4 x0 = p[0], x1 = p[1], x2 = p[2], x3 = p[3];
                float av[16] = {x0.x,x0.y,x0.z,x0.w, x1.x,x1.y,x1.z,x1.w,
                                x2.x,x2.y,x2.z,x2.w, x3.x,x3.y,x3.z,x3.w};
                if (AMODE == 3) {
                    if (Apre) {
                        const float4* q = (const float4*)(Apre + (size_t)gr*K + k0 + kc);
                        float4 p0 = q[0], p1 = q[1], p2 = q[2], p3 = q[3];
                        float pv[16] = {p0.x,p0.y,p0.z,p0.w, p1.x,p1.y,p1.z,p1.w,
                                        p2.x,p2.y,p2.z,p2.w, p3.x,p3.y,p3.z,p3.w};
                        #pragma unroll
                        for (int j = 0; j < 16; ++j) av[j] += pv[j];
                    }
                    float2 st = ast[gr];
                    const float4* gp = (const float4*)(ag + k0 + kc);
                    const float4* bp = (const float4*)(ab + k0 + kc);
                    float4 g0 = gp[0], g1 = gp[1], g2 = gp[2], g3 = gp[3];
                    float4 b0 = bp[0], b1 = bp[1], b2 = bp[2], b3 = bp[3];
                    float gv[16] = {g0.x,g0.y,g0.z,g0.w, g1.x,g1.y,g1.z,g1.w,
                                    g2.x,g2.y,g2.z,g2.w, g3.x,g3.y,g3.z,g3.w};
                    float bv[16] = {b0.x,b0.y,b0.z,b0.w, b1.x,b1.y,b1.z,b1.w,
                                    b2.x,b2.y,b2.z,b2.w, b3.x,b3.y,b3.z,b3.w};
                    #pragma unroll
                    for (int j = 0; j < 16; ++j)
                        av[j] = (av[j] - st.x)*st.y*gv[j] + bv[j];
                    if (Apost) {
                        const float4* q = (const float4*)(Apost + (size_t)gr*K + k0 + kc);
                        float4 p0 = q[0], p1 = q[1], p2 = q[2], p3 = q[3];
                        float pv[16] = {p0.x,p0.y,p0.z,p0.w, p1.x,p1.y,p1.z,p1.w,
                                        p2.x,p2.y,p2.z,p2.w, p3.x,p3.y,p3.z,p3.w};
                        #pragma unroll
                        for (int j = 0; j < 16; ++j) av[j] += pv[j];
                    }
                }
                #pragma unroll
                for (int j = 0; j < 8; ++j) { a0[j] = f2bs(av[j]); a1[j] = f2bs(av[8+j]); }
            }
        }
        *(short8*)&As[r*LDK + kc]     = a0;
        *(short8*)&As[r*LDK + kc + 8] = a1;
        short8 b0 = z8, b1 = z8;
        if (gc < N) {
            const short8* p = (const short8*)(Wt + (size_t)gc*K + k0 + kc);
            b0 = p[0]; b1 = p[1];
        }
        *(short8*)&Bs[r*LDK + kc]     = b0;
        *(short8*)&Bs[r*LDK + kc + 8] = b1;
        __syncthreads();
        #pragma unroll
        for (int kb = 0; kb < 64; kb += 32) {
            short8 af[2], bfr[2];
            #pragma unroll
            for (int mi = 0; mi < 2; ++mi)
                af[mi] = *(const short8*)&As[(wm*32 + mi*16 + l16)*LDK + kb + quad*8];
            #pragma unroll
            for (int ni = 0; ni < 2; ++ni)
                bfr[ni] = *(const short8*)&Bs[(wn*32 + ni*16 + l16)*LDK + kb + quad*8];
            #pragma unroll
            for (int mi = 0; mi < 2; ++mi)
                #pragma unroll
                for (int ni = 0; ni < 2; ++ni)
                    acc[mi][ni] = __builtin_amdgcn_mfma_f32_16x16x32_bf16(
                        af[mi], bfr[ni], acc[mi][ni], 0, 0, 0);
        }
        __syncthreads();
    }
    #pragma unroll
    for (int mi = 0; mi < 2; ++mi) {
        int rbase = row0 + wm*32 + mi*16 + quad*4;
        #pragma unroll
        for (int ni = 0; ni < 2; ++ni) {
            int c = col0 + wn*32 + ni*16 + l16;
            if (c >= N) continue;
            #pragma unroll
            for (int r2 = 0; r2 < 4; ++r2) {
                int rr = rbase + r2;
                if (rr >= M) continue;
                float v = acc[mi][ni][r2];
                if (bias) v += bias[c];
                if (act) v = 0.5f*v*(1.f + tanhf(0.7978845608028654f*(v + 0.044715f*v*v*v)));
                if (res) v += res[(size_t)rr*N + c];
                if (cbf) ((bf16*)Cout)[(size_t)rr*N + c] = __float2bfloat16(v);
                else     ((float*)Cout)[(size_t)rr*N + c] = v;
            }
        }
    }
}

// ---------- MFMA GEMM 128x128 with fused LN on A (value GEMM) ----------
__global__ __launch_bounds__(256) void mgemm128_kernel(
    const void* __restrict__ Asrc, const int* __restrict__ flag,
    const float2* __restrict__ stats, const float* __restrict__ g, const float* __restrict__ bvec,
    const short* __restrict__ Wt, const float* __restrict__ bias,
    bf16* __restrict__ C, int K, int N){
    __shared__ short As[128*LDK];
    __shared__ short Bs[128*LDK];
    __shared__ float gs[256], bs[256];
    int tid = threadIdx.x;
    int f = flag[0];
    int wave = tid >> 6, lane = tid & 63;
    int wm = wave >> 1, wn = wave & 1;
    int quad = lane >> 4, l16 = lane & 15;
    int row0 = blockIdx.x*128, col0 = blockIdx.y*128;
    if (tid < K) { gs[tid] = g[tid]; bs[tid] = bvec[tid]; }
    floatx4 acc[4][4];
    #pragma unroll
    for (int i = 0; i < 4; ++i)
        #pragma unroll
        for (int j = 0; j < 4; ++j)
            acc[i][j] = (floatx4){0.f,0.f,0.f,0.f};
    __syncthreads();

    for (int k0 = 0; k0 < K; k0 += 64) {
        #pragma unroll
        for (int i = 0; i < 2; ++i) {
            int idx = tid + i*256;
            int r = idx >> 2;
            int kc = (idx & 3) * 16;
            int gr = row0 + r;
            float2 st = stats[gr];
            float av[16];
            if (f) {
                const float4* p = (const float4*)((const float*)Asrc + (size_t)gr*K + k0 + kc);
                float4 x0 = p[0], x1 = p[1], x2 = p[2], x3 = p[3];
                av[0]=x0.x; av[1]=x0.y; av[2]=x0.z; av[3]=x0.w;
                av[4]=x1.x; av[5]=x1.y; av[6]=x1.z; av[7]=x1.w;
                av[8]=x2.x; av[9]=x2.y; av[10]=x2.z; av[11]=x2.w;
                av[12]=x3.x; av[13]=x3.y; av[14]=x3.z; av[15]=x3.w;
            } else {
                const short8* p = (const short8*)((const short*)Asrc + (size_t)gr*K + k0 + kc);
                short8 s0 = p[0], s1 = p[1];
                #pragma unroll
                for (int j = 0; j < 8; ++j) {
                    av[j] = bs2f(s0[j]); av[8+j] = bs2f(s1[j]);
                }
            }
            short8 a0, a1;
            #pragma unroll
            for (int j = 0; j < 16; ++j) {
                float v = (av[j] - st.x) * st.y * gs[k0+kc+j] + bs[k0+kc+j];
                if (j < 8) a0[j] = f2bs(v); else a1[j-8] = f2bs(v);
            }
            *(short8*)&As[r*LDK + kc]     = a0;
            *(short8*)&As[r*LDK + kc + 8] = a1;
            int gc = col0 + r;
            const short8* pb = (const short8*)(Wt + (size_t)gc*K + k0 + kc);
            *(short8*)&Bs[r*LDK + kc]     = pb[0];
            *(short8*)&Bs[r*LDK + kc + 8] = pb[1];
        }
        __syncthreads();
        #pragma unroll
        for (int kb = 0; kb < 64; kb += 32) {
            short8 af[4], bfr[4];
            #pragma unroll
            for (int mi = 0; mi < 4; ++mi)
                af[mi] = *(const short8*)&As[(wm*64 + mi*16 + l16)*LDK + kb + quad*8];
            #pragma unroll
            for (int ni = 0; ni < 4; ++ni)
                bfr[ni] = *(const short8*)&Bs[(wn*64 + ni*16 + l16)*LDK + kb + quad*8];
            #pragma unroll
            for (int mi = 0; mi < 4; ++mi)
                #pragma unroll
                for (int ni = 0; ni < 4; ++ni)
                    acc[mi][ni] = __builtin_amdgcn_mfma_f32_16x16x32_bf16(
                        af[mi], bfr[ni], acc[mi][ni], 0, 0, 0);
        }
        __syncthreads();
    }
    #pragma unroll
    for (int mi = 0; mi < 4; ++mi) {
        int rbase = row0 + wm*64 + mi*16 + quad*4;
        #pragma unroll
        for (int ni = 0; ni < 4; ++ni) {
            int c = col0 + wn*64 + ni*16 + l16;
            float bv = bias[c];
            #pragma unroll
            for (int r2 = 0; r2 < 4; ++r2)
                C[(size_t)(rbase + r2)*N + c] = __float2bfloat16(acc[mi][ni][r2] + bv);
        }
    }
}

// ---------- fused flash attention: one dispatch per layer ----------
// grid (16 qtiles, 32 nh); block 256 = 4 waves; each wave owns 16 q-rows.
// S never materialized: online softmax (f32 m/l), K/V streamed in 64-key LDS tiles,
// P round-tripped through per-wave-private LDS rows (pv2's proven fragment layouts).
__global__ __launch_bounds__(256) void fattn_kernel(const short* __restrict__ qkv,
                                                    float* __restrict__ out){
    int nh = blockIdx.y;
    int n = nh >> 3, h = nh & 7;
    int q0 = blockIdx.x * 64;
    __shared__ short Ks[64*40];
    __shared__ short VsT[32*72];
    __shared__ short Ps[64*72];
    int tid = threadIdx.x;
    int wave = tid >> 6, lane = tid & 63;
    int quad = lane >> 4, l16 = lane & 15;
    int r = tid >> 2, c8 = (tid & 3) * 8;
    const short8 z8 = {0,0,0,0,0,0,0,0};

    // Q A-fragment: row=l16 -> q=q0+wave*16+l16, k=quad*8..+7. Pre-scaled. Hoisted.
    short8 qf = z8;
    {
        int gq = q0 + wave*16 + l16;
        if (gq < LQ) {
            short8 s = *(const short8*)(qkv + ((size_t)(n*LQ+gq))*768 + h*32 + quad*8);
            #pragma unroll
            for (int j = 0; j < 8; ++j) qf[j] = f2bs(bs2f(s[j]) * ATT_SCALE);
        }
    }
    floatx4 acc[2];
    acc[0] = (floatx4){0.f,0.f,0.f,0.f};
    acc[1] = (floatx4){0.f,0.f,0.f,0.f};
    float m[4], lsum[4];
    #pragma unroll
    for (int i = 0; i < 4; ++i) { m[i] = -3.0e38f; lsum[i] = 0.f; }

    for (int k0 = 0; k0 < LQ; k0 += 64) {
        {   // stage K tile [64 keys x 32 d] and V^T tile [32 d x 64 keys]
            int gk = k0 + r;
            short8 kv = z8, vv = z8;
            if (gk < LQ) {
                const short* rp = qkv + ((size_t)(n*LQ+gk))*768;
                kv = *(const short8*)(rp + 256 + h*32 + c8);
                vv = *(const short8*)(rp + 512 + h*32 + c8);
            }
            *(short8*)&Ks[r*40 + c8] = kv;
            #pragma unroll
            for (int j = 0; j < 8; ++j) VsT[(c8+j)*72 + r] = vv[j];
        }
        __syncthreads();
        // S tiles: lane holds q=quad*4+r2 (rows), key=kg*16+l16 (col)
        floatx4 s4[4];
        #pragma unroll
        for (int kg = 0; kg < 4; ++kg) {
            short8 bfr = *(const short8*)&Ks[(kg*16 + l16)*40 + quad*8];
            s4[kg] = __builtin_amdgcn_mfma_f32_16x16x32_bf16(
                qf, bfr, (floatx4){0.f,0.f,0.f,0.f}, 0, 0, 0);
        }
        if (k0 + 64 > LQ) {   // mask padded keys (last tile only)
            #pragma unroll
            for (int kg = 0; kg < 4; ++kg)
                if (k0 + kg*16 + l16 >= LQ)
                    s4[kg] = (floatx4){-3.0e38f,-3.0e38f,-3.0e38f,-3.0e38f};
        }
        // online softmax update: per-lane max over its 4 key-groups, reduce over l16
        float fac[4], psum[4];
        #pragma unroll
        for (int r2 = 0; r2 < 4; ++r2) {
            float v = fmaxf(fmaxf(s4[0][r2], s4[1][r2]), fmaxf(s4[2][r2], s4[3][r2]));
            v = fmaxf(v, __shfl_xor(v, 1, 64));
            v = fmaxf(v, __shfl_xor(v, 2, 64));
            v = fmaxf(v, __shfl_xor(v, 4, 64));
            v = fmaxf(v, __shfl_xor(v, 8, 64));
            float mn = fmaxf(m[r2], v);
            fac[r2] = __expf(m[r2] - mn);
            m[r2] = mn;
            psum[r2] = 0.f;
        }
        // P = exp(S - m): write bf16 P to this wave's private Ps rows
        #pragma unroll
        for (int kg = 0; kg < 4; ++kg)
            #pragma unroll
            for (int r2 = 0; r2 < 4; ++r2) {
                float pv = __expf(s4[kg][r2] - m[r2]);
                psum[r2] += pv;
                Ps[(wave*16 + quad*4 + r2)*72 + kg*16 + l16] = f2bs(pv);
            }
        #pragma unroll
        for (int r2 = 0; r2 < 4; ++r2) {
            psum[r2] += __shfl_xor(psum[r2], 1, 64);
            psum[r2] += __shfl_xor(psum[r2], 2, 64);
            psum[r2] += __shfl_xor(psum[r2], 4, 64);
            psum[r2] += __shfl_xor(psum[r2], 8, 64);
            lsum[r2] = lsum[r2]*fac[r2] + psum[r2];
        }
        #pragma unroll
        for (int ni = 0; ni < 2; ++ni)
            #pragma unroll
            for (int r2 = 0; r2 < 4; ++r2)
                acc[ni][r2] *= fac[r2];
        // PV: A=P (rows=q=l16), B=V^T (rows=d) -> C[q][d], same q-ownership as S
        #pragma unroll
        for (int kb = 0; kb < 64; kb += 32) {
            short8 pf = *(const short8*)&Ps[(wave*16 + l16)*72 + kb + quad*8];
            #pragma unroll
            for (int ni = 0; ni < 2; ++ni) {
                short8 vf = *(const short8*)&VsT[(ni*16 + l16)*72 + kb + quad*8];
                acc[ni] = __builtin_amdgcn_mfma_f32_16x16x32_bf16(pf, vf, acc[ni], 0, 0, 0);
            }
        }
        __syncthreads();
    }
    #pragma unroll
    for (int r2 = 0; r2 < 4; ++r2) {
        int row = q0 + wave*16 + quad*4 + r2;
        if (row >= LQ) continue;
        float inv = 1.f / lsum[r2];
        #pragma unroll
        for (int ni = 0; ni < 2; ++ni)
            out[((size_t)(n*LQ+row))*256 + h*32 + ni*16 + l16] = acc[ni][r2] * inv;
    }
}

// ---------- deformable sampling: branch-free clamped corners ----------
__global__ __launch_bounds__(256) void sample2_kernel(
        const bf16* __restrict__ value, const float* __restrict__ offaw,
        const float* __restrict__ cp, float* __restrict__ out){
    int nq = blockIdx.x;
    int n = nq / LQ;
    int d = threadIdx.x & 31, h = threadIdx.x >> 5;
    float cx = cp[nq*2], cy = cp[nq*2+1];
    const float* rowp = offaw + (size_t)nq*480;
    float o0 = rowp[h*40 + d];
    float o1 = (d < 8) ? rowp[h*40 + 32 + d] : 0.f;
    float logit = (d < 20) ? rowp[320 + h*20 + d] : -3.0e38f;
    float mx = logit;
    #pragma unroll
    for (int off = 16; off; off >>= 1) mx = fmaxf(mx, __shfl_xor(mx, off, 32));
    float p = (d < 20) ? __expf(logit - mx) : 0.f;
    float sm = p;
    #pragma unroll
    for (int off = 16; off; off >>= 1) sm += __shfl_xor(sm, off, 32);
    p *= (1.f / sm);

    const int HW[5] = {128,64,32,16,8};
    const int ST[5] = {0,16384,20480,21504,21760};
    float acc = 0.f;
    #pragma unroll
    for (int l = 0; l < 5; ++l) {
        int hw = HW[l];
        float fhw = (float)hw;
        size_t vb = ((size_t)n*LIN + ST[l]) * 256 + h*32 + d;
        #pragma unroll
        for (int pi = 0; pi < 4; ++pi) {
            const int idx = l*4 + pi;
            float w  = __shfl(p, idx, 32);
            float ox = (2*idx < 32)   ? __shfl(o0, 2*idx, 32)   : __shfl(o1, 2*idx-32, 32);
            float oy = (2*idx+1 < 32) ? __shfl(o0, 2*idx+1, 32) : __shfl(o1, 2*idx+1-32, 32);
            float gx = cx*fhw + ox - 0.5f;
            float gy = cy*fhw + oy - 0.5f;
            float x0f = floorf(gx), y0f = floorf(gy);
            float lx = gx - x0f, ly = gy - y0f;
            int x0 = (int)x0f, y0 = (int)y0f;
            int x1 = x0 + 1, y1 = y0 + 1;
            bool bx0 = (unsigned)x0 < (unsigned)hw, bx1 = (unsigned)x1 < (unsigned)hw;
            bool by0 = (unsigned)y0 < (unsigned)hw, by1 = (unsigned)y1 < (unsigned)hw;
            int x0c = min(max(x0, 0), hw-1), x1c = min(max(x1, 0), hw-1);
            int y0c = min(max(y0, 0), hw-1), y1c = min(max(y1, 0), hw-1);
            float v00 = __bfloat162float(value[vb + (size_t)(y0c*hw + x0c)*256]);
            float v01 = __bfloat162float(value[vb + (size_t)(y0c*hw + x1c)*256]);
            float v10 = __bfloat162float(value[vb + (size_t)(y1c*hw + x0c)*256]);
            float v11 = __bfloat162float(value[vb + (size_t)(y1c*hw + x1c)*256]);
            float w00 = (bx0 && by0) ? (1.f-ly)*(1.f-lx)*w : 0.f;
            float w01 = (bx1 && by0) ? (1.f-ly)*lx*w       : 0.f;
            float w10 = (bx0 && by1) ? ly*(1.f-lx)*w       : 0.f;
            float w11 = (bx1 && by1) ? ly*lx*w             : 0.f;
            acc = fmaf(w00, v00, acc);
            acc = fmaf(w01, v01, acc);
            acc = fmaf(w10, v10, acc);
            acc = fmaf(w11, v11, acc);
        }
    }
    out[(size_t)nq*256 + h*32 + d] = acc;
}

// ---------- final store ----------
__global__ void final_kernel(const float* __restrict__ in, void* __restrict__ out,
                             int n, const int* __restrict__ flag){
    int f = flag[0];
    int i = blockIdx.x*256 + threadIdx.x;
    if (i >= n) return;
    float v = in[i];
    if (!isfinite(v)) v = 0.f;
    if (f) ((float*)out)[i] = v;
    else   ((bf16*)out)[i] = __float2bfloat16(v);
}

extern "C" void kernel_launch(void* const* d_in, const int* in_sizes, int n_in,
                              void* d_out, int out_size, void* d_ws, size_t ws_size,
                              hipStream_t stream){
    const void* x_raw  = d_in[0];
    const void* src    = d_in[1];
    const void* cp_raw = d_in[2];
    char* ws = (char*)d_ws;
    size_t off = 0;
    auto alloc = [&](size_t bytes){ size_t p = off; off += (bytes + 255) & ~(size_t)255; return p; };
    int*   flag  = (int*)(ws + alloc(256));
    float* xf    = (float*)(ws + alloc((size_t)ROWS_X*DIM*4));
    float* pe    = (float*)(ws + alloc((size_t)ROWS_X*DIM*4));
    float* tmp   = (float*)(ws + alloc((size_t)ROWS_X*DIM*4));
    bf16*  qkv   = (bf16*)(ws + alloc((size_t)ROWS_X*768*2));
    bf16*  ffh   = (bf16*)(ws + alloc((size_t)ROWS_X*MLPD*2));
    float* offaw = (float*)(ws + alloc((size_t)ROWS_X*480*4));
    float2* stats = (float2*)(ws + alloc((size_t)ROWS_SRC*8));
    float2* xst  = (float2*)(ws + alloc((size_t)ROWS_X*8));
    float* cpf   = (float*)(ws + alloc((size_t)ROWS_X*2*4));
    float* oab   = (float*)(ws + alloc((size_t)2*480*4));
    const int sidx[13] = {5,6,7,8,11,12,13,19,21,22,23,25,27};
    const int ssz[13]  = {512,256,512,512,512,512,512,512,512,512,512,1024,512};
    float* sp[13];
    for (int j = 0; j < 13; ++j) sp[j] = (float*)(ws + alloc((size_t)ssz[j]*4));
    short* qkvT = (short*)(ws + alloc((size_t)2*768*256*2));
    short* outT = (short*)(ws + alloc((size_t)2*256*256*2));
    short* oawT = (short*)(ws + alloc((size_t)2*480*256*2));
    short* valT = (short*)(ws + alloc((size_t)2*256*256*2));
    short* opT  = (short*)(ws + alloc((size_t)2*256*256*2));
    short* ff1T = (short*)(ws + alloc((size_t)2*512*256*2));
    short* ff2T = (short*)(ws + alloc((size_t)2*256*512*2));
    bf16*  val  = (bf16*)(ws + alloc((size_t)ROWS_SRC*DIM*2));
    (void)ws_size; (void)in_sizes; (void)n_in; (void)out_size;

    detect_kernel<<<1, 256, 0, stream>>>(x_raw, flag);
    conv_kernel<<<(ROWS_X*DIM+255)/256, 256, 0, stream>>>(x_raw, xf, ROWS_X*DIM, flag);
    PTab pt;
    for (int j = 0; j < 13; ++j) { pt.src[j] = d_in[sidx[j]]; pt.dst[j] = sp[j]; pt.n[j] = ssz[j]; }
    pt.src[13] = cp_raw; pt.dst[13] = cpf; pt.n[13] = ROWS_X*2;
    convs_kernel<<<dim3(32,14), 256, 0, stream>>>(pt, flag);
    catb_kernel<<<dim3(2,2), 256, 0, stream>>>(d_in[15], d_in[17], flag, oab);
    {
        WT wt;
        const int widx[8] = {9,10,14,16,18,20,24,26};
        short* wdst[8] = {qkvT, outT, oawT, oawT, valT, opT, ff1T, ff2T};
        const int wK[8]  = {256,256,256,256,256,256,256,512};
        const int wN[8]  = {768,256,320,160,256,256,512,256};
        const int wld[8] = {768,256,480,480,256,256,512,256};
        const int wro[8] = {0,0,0,320,0,0,0,0};
        for (int j = 0; j < 8; ++j) {
            wt.src[j] = d_in[widx[j]]; wt.dst[j] = wdst[j];
            wt.K[j] = wK[j]; wt.N[j] = wN[j]; wt.ld[j] = wld[j]; wt.ro[j] = wro[j];
        }
        wtransall_kernel<<<dim3(16,24,16), 256, 0, stream>>>(wt, flag);
    }

    float* pos_w = sp[0];  float* pos_b = sp[1];
    float* ln1_g = sp[2];  float* ln1_b = sp[3];
    float* out_b = sp[4];
    float* ln2_g = sp[5];  float* ln2_b = sp[6];
    float* val_b = sp[7];  float* op_b  = sp[8];
    float* ln3_g = sp[9];  float* ln3_b = sp[10];
    float* ff_b1 = sp[11]; float* ff_b2 = sp[12];
    (void)pos_w; (void)pos_b;

    pe_kernel<<<ROWS_X, 256, 0, stream>>>(cp_raw, d_in[5], d_in[6], flag, pe);
    stats2_kernel<<<ROWS_SRC/4, 256, 0, stream>>>(src, flag, stats);

    int gmx = (ROWS_X + 63) / 64;   // 63
    for (int i = 0; i < 2; ++i) {
        // --- self attention: qkv = LN(xf+pe;ln1) @ qkv_w (LN fused) ---
        xstats_kernel<<<ROWS_X/4, 256, 0, stream>>>(xf, pe, xst);
        mgemm_kernel<3><<<dim3(gmx,12), 256, 0, stream>>>(
            xf, xst, ln1_g + i*DIM, ln1_b + i*DIM, pe, nullptr,
            qkvT + (size_t)i*768*256, nullptr, nullptr, qkv, ROWS_X, 256, 768, 0, 1);
        fattn_kernel<<<dim3(16,32), 256, 0, stream>>>((const short*)qkv, tmp);
        mgemm_kernel<0><<<dim3(gmx,4), 256, 0, stream>>>(
            tmp, nullptr, nullptr, nullptr, nullptr, nullptr,
            outT + (size_t)i*256*256, out_b + i*DIM, xf, xf, ROWS_X, 256, 256, 0, 0);
        // --- deformable cross attention ---
        mgemm128_kernel<<<dim3(ROWS_SRC/128, 2), 256, 0, stream>>>(
            src, flag, stats, ln2_g + i*DIM, ln2_b + i*DIM,
            valT + (size_t)i*256*256, val_b + i*DIM, val, 256, 256);
        // offaw = (LN(xf;ln2)+pe) @ [off|aw]_w (LN+pe fused)
        xstats_kernel<<<ROWS_X/4, 256, 0, stream>>>(xf, nullptr, xst);
        mgemm_kernel<3><<<dim3(gmx,8), 256, 0, stream>>>(
            xf, xst, ln2_g + i*DIM, ln2_b + i*DIM, nullptr, pe,
            oawT + (size_t)i*480*256, oab + i*480, nullptr, offaw, ROWS_X, 256, 480, 0, 0);
        sample2_kernel<<<ROWS_X, 256, 0, stream>>>(val, offaw, cpf, tmp);
        mgemm_kernel<0><<<dim3(gmx,4), 256, 0, stream>>>(
            tmp, nullptr, nullptr, nullptr, nullptr, nullptr,
            opT + (size_t)i*256*256, op_b + i*DIM, xf, xf, ROWS_X, 256, 256, 0, 0);
        // --- feedforward: ffh = gelu(LN(xf;ln3) @ ff_w1) (LN fused) ---
        xstats_kernel<<<ROWS_X/4, 256, 0, stream>>>(xf, nullptr, xst);
        mgemm_kernel<3><<<dim3(gmx,8), 256, 0, stream>>>(
            xf, xst, ln3_g + i*DIM, ln3_b + i*DIM, nullptr, nullptr,
            ff1T + (size_t)i*512*256, ff_b1 + i*MLPD, nullptr, ffh, ROWS_X, 256, 512, 1, 1);
        mgemm_kernel<2><<<dim3(gmx,4), 256, 0, stream>>>(
            ffh, nullptr, nullptr, nullptr, nullptr, nullptr,
            ff2T + (size_t)i*256*512, ff_b2 + i*DIM, xf, xf, ROWS_X, 512, 256, 0, 0);
    }
    final_kernel<<<(ROWS_X*DIM+255)/256, 256, 0, stream>>>(xf, d_out, ROWS_X*DIM, flag);
}